// Round 4
// baseline (119.166 us; speedup 1.0000x reference)
//
#include <hip/hip_runtime.h>

// CliffordLayerNorm: per-256-float block, per-grade (popcount) layernorm.
// One wave handles 16 MV blocks (4 lanes each). Lane l (0..3) of a group
// holds the 64 elements m = 16k + 4l + j (k in 0..15, j in 0..3).
// popcount(m) = pc(k) + pc(l) + pc(j): each lane's elements span relative
// grades 0..6 above base p = pc(l) in {0,1,2}. Per-grade sums reduced with a
// 2-step Pascal butterfly over the 2 lane bits (array grows 7 -> 9).
//
// Round-4: 1 task per wave (round-3's 2-deep pipeline was defeated by the
// compiler -- VGPR=88 proves B's loads were sunk into A's compute), keep
// nontemporal stores (output never re-read; don't evict L3-resident x),
// double wave count for TLP: 16384 waves, VGPR ~64-72 -> 7-8 waves/SIMD.

typedef float f32x4 __attribute__((ext_vector_type(4)));

static __device__ __forceinline__ float shx(float v, int m) {
    return __shfl_xor(v, m, 64);
}

// Pascal merge over lane bit BM: b[j] = hi ? a[j-1] : a[j] (a[-1]=a[L]=0),
// then a'[j] = b[j] + partner(b[j]). Length L -> L+1.
template <int BM, int L>
static __device__ __forceinline__ void pascal_step(float (&s)[9], float (&q)[9],
                                                   bool hi) {
#pragma unroll
    for (int j = L; j >= 0; --j) {
        float bs = (j == 0) ? (hi ? 0.0f : s[0])
                 : (j == L) ? (hi ? s[L - 1] : 0.0f)
                            : (hi ? s[j - 1] : s[j]);
        float bq = (j == 0) ? (hi ? 0.0f : q[0])
                 : (j == L) ? (hi ? q[L - 1] : 0.0f)
                            : (hi ? q[j - 1] : q[j]);
        s[j] = bs;
        q[j] = bq;
    }
#pragma unroll
    for (int j = 0; j <= L; ++j) {
        s[j] += shx(s[j], BM);
        q[j] += shx(q[j], BM);
    }
}

__global__ __launch_bounds__(256) void cliff_ln_kernel(
    const float* __restrict__ x, const float* __restrict__ w,
    const float* __restrict__ b, float* __restrict__ out, int nblk)
{
    const int lane = threadIdx.x & 63;
    const int grp  = lane >> 2;
    const int l    = lane & 3;
    const int p    = __popc(l);
    const bool p1 = (p & 1) != 0, p2 = (p & 2) != 0;
    const bool hi1 = (l & 1) != 0, hi2 = (l & 2) != 0;
    const int wave_id     = (blockIdx.x * blockDim.x + threadIdx.x) >> 6;
    const int total_waves = (gridDim.x * blockDim.x) >> 6;

    float wg[9], bg[9];
#pragma unroll
    for (int g = 0; g < 9; ++g) { wg[g] = w[g]; bg[g] = b[g]; }

    constexpr int PC[16] = {0,1,1,2,1,2,2,3,1,2,2,3,2,3,3,4};
    const float invc[9] = {1.0f, 0.125f, 1.0f/28.0f, 1.0f/56.0f, 1.0f/70.0f,
                           1.0f/56.0f, 1.0f/28.0f, 0.125f, 1.0f};

    const int ntask = nblk >> 4;
    for (int task = wave_id; task < ntask; task += total_waves) {
        const int blk = (task << 4) + grp;
        const f32x4* xb = reinterpret_cast<const f32x4*>(x) + (size_t)blk * 64;

        f32x4 xv[16];
#pragma unroll
        for (int k = 0; k < 16; ++k) xv[k] = xb[4 * k + l];

        float s[9], q[9];
#pragma unroll
        for (int j = 0; j < 9; ++j) { s[j] = 0.0f; q[j] = 0.0f; }

#define ACC1(v, r) { s[r] += (v); q[r] = fmaf((v), (v), q[r]); }
#pragma unroll
        for (int k = 0; k < 16; ++k) {
            const int r = PC[k];
            ACC1(xv[k][0], r + 0)
            ACC1(xv[k][1], r + 1)
            ACC1(xv[k][2], r + 1)
            ACC1(xv[k][3], r + 2)
        }
#undef ACC1

        pascal_step<1, 7>(s, q, hi1);
        pascal_step<2, 8>(s, q, hi2);

        float scl[9], sft[9];
#pragma unroll
        for (int g = 0; g < 9; ++g) {
            float mean = s[g] * invc[g];
            float var  = fmaf(-mean, mean, q[g] * invc[g]);
            var = fmaxf(var, 0.0f);
            float inv = rsqrtf(var + 1e-5f);
            float sc  = inv * wg[g];
            scl[g] = sc;
            sft[g] = fmaf(-mean, sc, bg[g]);
        }

        // shift down by p = pc(l) in 0..2; only relative grades 0..6 consumed
#pragma unroll
        for (int j = 0; j < 7; ++j) { scl[j] = p2 ? scl[j+2] : scl[j];
                                      sft[j] = p2 ? sft[j+2] : sft[j]; }
#pragma unroll
        for (int j = 0; j < 7; ++j) { scl[j] = p1 ? scl[j+1] : scl[j];
                                      sft[j] = p1 ? sft[j+1] : sft[j]; }

        f32x4* ob = reinterpret_cast<f32x4*>(out) + (size_t)blk * 64;
#pragma unroll
        for (int k = 0; k < 16; ++k) {
            const int r = PC[k];
            f32x4 o;
            o[0] = fmaf(xv[k][0], scl[r + 0], sft[r + 0]);
            o[1] = fmaf(xv[k][1], scl[r + 1], sft[r + 1]);
            o[2] = fmaf(xv[k][2], scl[r + 1], sft[r + 1]);
            o[3] = fmaf(xv[k][3], scl[r + 2], sft[r + 2]);
            __builtin_nontemporal_store(o, &ob[4 * k + l]);
        }
    }
}

extern "C" void kernel_launch(void* const* d_in, const int* in_sizes, int n_in,
                              void* d_out, int out_size, void* d_ws, size_t ws_size,
                              hipStream_t stream) {
    const float* x = (const float*)d_in[0];
    const float* w = (const float*)d_in[1];
    const float* b = (const float*)d_in[2];
    float* out = (float*)d_out;
    const int n = in_sizes[0];
    const int nblk = n / 256;
    const int ntask = nblk / 16;           // 16384 for the bench shape
    int wgs = (ntask + 3) / 4;             // 1 task per wave, 4 waves per WG
    if (wgs > 16384) wgs = 16384;
    if (wgs < 1) wgs = 1;
    hipLaunchKernelGGL(cliff_ln_kernel, dim3(wgs), dim3(256), 0, stream,
                       x, w, b, out, nblk);
}

// Round 5
// 97.136 us; speedup vs baseline: 1.2268x; 1.2268x over previous
//
#include <hip/hip_runtime.h>

// CliffordLayerNorm: per-256-float block, per-grade (popcount) layernorm.
// One wave handles 16 MV blocks (4 lanes each). Lane l (0..3) of a group
// holds the 64 elements m = 16k + 4l + j (k in 0..15, j in 0..3).
// popcount(m) = pc(k) + pc(l) + pc(j): each lane's elements span relative
// grades 0..6 above base p = pc(l) in {0,1,2}. Per-grade sums reduced with a
// 2-step Pascal butterfly over the 2 lane bits (array grows 7 -> 9).
//
// Round-5: enforce the 2-task-per-wave pipeline that won in R3.
// Flat kernel (even ntask): straight-line single-BB body -- 32 loads for two
// CONSECUTIVE tasks, sched_barrier(0), then process both. Single BB defeats
// IR/Machine sinking (R3's VGPR=88 showed the compiler kept only half of B
// resident); sched_barrier pins all loads before any compute.

typedef float f32x4 __attribute__((ext_vector_type(4)));

static __device__ __forceinline__ float shx(float v, int m) {
    return __shfl_xor(v, m, 64);
}

// Pascal merge over lane bit BM: b[j] = hi ? a[j-1] : a[j] (a[-1]=a[L]=0),
// then a'[j] = b[j] + partner(b[j]). Length L -> L+1.
template <int BM, int L>
static __device__ __forceinline__ void pascal_step(float (&s)[9], float (&q)[9],
                                                   bool hi) {
#pragma unroll
    for (int j = L; j >= 0; --j) {
        float bs = (j == 0) ? (hi ? 0.0f : s[0])
                 : (j == L) ? (hi ? s[L - 1] : 0.0f)
                            : (hi ? s[j - 1] : s[j]);
        float bq = (j == 0) ? (hi ? 0.0f : q[0])
                 : (j == L) ? (hi ? q[L - 1] : 0.0f)
                            : (hi ? q[j - 1] : q[j]);
        s[j] = bs;
        q[j] = bq;
    }
#pragma unroll
    for (int j = 0; j <= L; ++j) {
        s[j] += shx(s[j], BM);
        q[j] += shx(q[j], BM);
    }
}

static __device__ __forceinline__ void process_task(
    const f32x4 (&xv)[16], float* __restrict__ out, int blk, int l,
    bool p1, bool p2, bool hi1, bool hi2,
    const float (&wg)[9], const float (&bg)[9])
{
    constexpr int PC[16] = {0,1,1,2,1,2,2,3,1,2,2,3,2,3,3,4};
    const float invc[9] = {1.0f, 0.125f, 1.0f/28.0f, 1.0f/56.0f, 1.0f/70.0f,
                           1.0f/56.0f, 1.0f/28.0f, 0.125f, 1.0f};

    float s[9], q[9];
#pragma unroll
    for (int j = 0; j < 9; ++j) { s[j] = 0.0f; q[j] = 0.0f; }

#define ACC1(v, r) { s[r] += (v); q[r] = fmaf((v), (v), q[r]); }
#pragma unroll
    for (int k = 0; k < 16; ++k) {
        const int r = PC[k];
        ACC1(xv[k][0], r + 0)
        ACC1(xv[k][1], r + 1)
        ACC1(xv[k][2], r + 1)
        ACC1(xv[k][3], r + 2)
    }
#undef ACC1

    pascal_step<1, 7>(s, q, hi1);
    pascal_step<2, 8>(s, q, hi2);

    float scl[9], sft[9];
#pragma unroll
    for (int g = 0; g < 9; ++g) {
        float mean = s[g] * invc[g];
        float var  = fmaf(-mean, mean, q[g] * invc[g]);
        var = fmaxf(var, 0.0f);
        float inv = rsqrtf(var + 1e-5f);
        float sc  = inv * wg[g];
        scl[g] = sc;
        sft[g] = fmaf(-mean, sc, bg[g]);
    }

    // shift down by p = pc(l) in 0..2; only relative grades 0..6 consumed
#pragma unroll
    for (int j = 0; j < 7; ++j) { scl[j] = p2 ? scl[j+2] : scl[j];
                                  sft[j] = p2 ? sft[j+2] : sft[j]; }
#pragma unroll
    for (int j = 0; j < 7; ++j) { scl[j] = p1 ? scl[j+1] : scl[j];
                                  sft[j] = p1 ? sft[j+1] : sft[j]; }

    f32x4* ob = reinterpret_cast<f32x4*>(out) + (size_t)blk * 64;
#pragma unroll
    for (int k = 0; k < 16; ++k) {
        const int r = PC[k];
        f32x4 o;
        o[0] = fmaf(xv[k][0], scl[r + 0], sft[r + 0]);
        o[1] = fmaf(xv[k][1], scl[r + 1], sft[r + 1]);
        o[2] = fmaf(xv[k][2], scl[r + 1], sft[r + 1]);
        o[3] = fmaf(xv[k][3], scl[r + 2], sft[r + 2]);
        __builtin_nontemporal_store(o, &ob[4 * k + l]);
    }
}

#define LOADT(buf, task) { \
    const f32x4* xb = reinterpret_cast<const f32x4*>(x) + \
        ((size_t)(((task) << 4) + grp)) * 64; \
    _Pragma("unroll") \
    for (int k = 0; k < 16; ++k) buf[k] = xb[4 * k + l]; }

// Fast path: ntask even, one wave per 2 consecutive tasks, straight-line body.
__global__ __launch_bounds__(256) void cliff_ln_flat(
    const float* __restrict__ x, const float* __restrict__ w,
    const float* __restrict__ b, float* __restrict__ out, int nwaves)
{
    const int lane = threadIdx.x & 63;
    const int grp  = lane >> 2;
    const int l    = lane & 3;
    const int p    = __popc(l);
    const bool p1 = (p & 1) != 0, p2 = (p & 2) != 0;
    const bool hi1 = (l & 1) != 0, hi2 = (l & 2) != 0;
    const int wid = (blockIdx.x * blockDim.x + threadIdx.x) >> 6;
    if (wid >= nwaves) return;
    const int tA = wid * 2, tB = tA + 1;

    float wg[9], bg[9];
#pragma unroll
    for (int g = 0; g < 9; ++g) { wg[g] = w[g]; bg[g] = b[g]; }

    f32x4 A[16], B[16];
    LOADT(A, tA)
    LOADT(B, tB)
    __builtin_amdgcn_sched_barrier(0);
    process_task(A, out, (tA << 4) + grp, l, p1, p2, hi1, hi2, wg, bg);
    process_task(B, out, (tB << 4) + grp, l, p1, p2, hi1, hi2, wg, bg);
}

// General fallback: grid-stride, 1 task per wave.
__global__ __launch_bounds__(256) void cliff_ln_loop(
    const float* __restrict__ x, const float* __restrict__ w,
    const float* __restrict__ b, float* __restrict__ out, int ntask)
{
    const int lane = threadIdx.x & 63;
    const int grp  = lane >> 2;
    const int l    = lane & 3;
    const int p    = __popc(l);
    const bool p1 = (p & 1) != 0, p2 = (p & 2) != 0;
    const bool hi1 = (l & 1) != 0, hi2 = (l & 2) != 0;
    const int wave_id     = (blockIdx.x * blockDim.x + threadIdx.x) >> 6;
    const int total_waves = (gridDim.x * blockDim.x) >> 6;

    float wg[9], bg[9];
#pragma unroll
    for (int g = 0; g < 9; ++g) { wg[g] = w[g]; bg[g] = b[g]; }

    for (int task = wave_id; task < ntask; task += total_waves) {
        f32x4 A[16];
        LOADT(A, task)
        process_task(A, out, (task << 4) + grp, l, p1, p2, hi1, hi2, wg, bg);
    }
}

#undef LOADT

extern "C" void kernel_launch(void* const* d_in, const int* in_sizes, int n_in,
                              void* d_out, int out_size, void* d_ws, size_t ws_size,
                              hipStream_t stream) {
    const float* x = (const float*)d_in[0];
    const float* w = (const float*)d_in[1];
    const float* b = (const float*)d_in[2];
    float* out = (float*)d_out;
    const int n = in_sizes[0];
    const int nblk = n / 256;
    const int ntask = nblk / 16;            // 16384 for the bench shape

    if ((nblk % 16 == 0) && (ntask % 2 == 0)) {
        const int nwaves = ntask / 2;       // 8192
        const int wgs = (nwaves + 3) / 4;   // 2048 WGs
        hipLaunchKernelGGL(cliff_ln_flat, dim3(wgs), dim3(256), 0, stream,
                           x, w, b, out, nwaves);
    } else {
        int wgs = (ntask + 3) / 4;
        if (wgs > 8192) wgs = 8192;
        if (wgs < 1) wgs = 1;
        hipLaunchKernelGGL(cliff_ln_loop, dim3(wgs), dim3(256), 0, stream,
                           x, w, b, out, ntask);
    }
}